// Round 1
// baseline (14.498 us; speedup 1.0000x reference)
//
#include <hip/hip_runtime.h>

#define GRID_H 128
#define GRID_W 128
#define N_POS  8192
#define EPS_F  1e-12f

__global__ __launch_bounds__(256) void MazeCollision_kernel(
    const float* __restrict__ pos,   // [N_POS, 2]
    const float* __restrict__ maze,  // [GRID_H, GRID_W]
    const float* __restrict__ rad_p, // [1]
    float* __restrict__ out)         // [1]
{
    const float rad = rad_p[0];
    const int tid = blockIdx.x * blockDim.x + threadIdx.x;

    float acc = 0.0f;
    if (tid < N_POS) {
        const float x = pos[2 * tid + 0];
        const float y = pos[2 * tid + 1];
        // cell center (i+0.5, j+0.5) can contribute only if |x-(i+0.5)| < rad
        // padded by floor/ceil so exact-boundary cells (contribution 0) are safe.
        int ilo = max(0, (int)floorf(x - 0.5f - rad));
        int ihi = min(GRID_H - 1, (int)ceilf(x - 0.5f + rad));
        int jlo = max(0, (int)floorf(y - 0.5f - rad));
        int jhi = min(GRID_W - 1, (int)ceilf(y - 0.5f + rad));
        for (int i = ilo; i <= ihi; ++i) {
            const float dx = x - ((float)i + 0.5f);
            const float dx2 = dx * dx;
            const int rowbase = i * GRID_W;
            for (int j = jlo; j <= jhi; ++j) {
                const float dy = y - ((float)j + 0.5f);
                const float d2 = dx2 + dy * dy;
                const float d = sqrtf(fmaxf(d2, EPS_F));
                const float pen = fmaxf(rad - d, 0.0f);
                acc += pen * maze[rowbase + j];
            }
        }
    }

    // 64-lane wave reduction
    #pragma unroll
    for (int off = 32; off > 0; off >>= 1)
        acc += __shfl_down(acc, off, 64);

    __shared__ float wave_sums[4];  // 256 threads / 64 lanes
    const int lane = threadIdx.x & 63;
    const int wave = threadIdx.x >> 6;
    if (lane == 0) wave_sums[wave] = acc;
    __syncthreads();

    if (threadIdx.x == 0) {
        const float s = wave_sums[0] + wave_sums[1] + wave_sums[2] + wave_sums[3];
        atomicAdd(out, s);
    }
}

extern "C" void kernel_launch(void* const* d_in, const int* in_sizes, int n_in,
                              void* d_out, int out_size, void* d_ws, size_t ws_size,
                              hipStream_t stream) {
    const float* pos  = (const float*)d_in[0];
    const float* maze = (const float*)d_in[1];
    const float* rad  = (const float*)d_in[2];
    float* out = (float*)d_out;

    // Harness poisons d_out once (0xAA) and never re-poisons; we accumulate
    // with atomics, so zero it each call (hipMemsetAsync is capture-safe).
    hipMemsetAsync(out, 0, (size_t)out_size * sizeof(float), stream);

    const int block = 256;
    const int grid = (N_POS + block - 1) / block;  // 32 blocks
    MazeCollision_kernel<<<grid, block, 0, stream>>>(pos, maze, rad, out);
}